// Round 1
// baseline (7428.316 us; speedup 1.0000x reference)
//
#include <hip/hip_runtime.h>
#include <math.h>

#define B_ 8
#define S_ 1024
#define D_ 1024
#define H_ 16
#define HD_ 64

// ---------------- LayerNorm: one block (256 thr) per row of 1024 ----------------
__global__ __launch_bounds__(256) void ln_kernel(const float* __restrict__ x,
                                                 const float* __restrict__ g,
                                                 const float* __restrict__ b,
                                                 float* __restrict__ out) {
  int row = blockIdx.x;
  const float* xr = x + (size_t)row * D_;
  float* outr = out + (size_t)row * D_;
  int tid = threadIdx.x;

  float4 v = ((const float4*)xr)[tid];  // 256 threads * 4 = 1024 elements
  float s = v.x + v.y + v.z + v.w;
  float ss = v.x * v.x + v.y * v.y + v.z * v.z + v.w * v.w;

  #pragma unroll
  for (int m = 1; m < 64; m <<= 1) {
    s += __shfl_xor(s, m);
    ss += __shfl_xor(ss, m);
  }
  __shared__ float red[10];
  int wid = tid >> 6;
  if ((tid & 63) == 0) { red[wid] = s; red[4 + wid] = ss; }
  __syncthreads();
  if (tid == 0) {
    float ts = red[0] + red[1] + red[2] + red[3];
    float tss = red[4] + red[5] + red[6] + red[7];
    float mu = ts * (1.0f / D_);
    float var = tss * (1.0f / D_) - mu * mu;
    red[8] = mu;
    red[9] = rsqrtf(var + 1e-5f);
  }
  __syncthreads();
  float mu = red[8], rstd = red[9];
  float4 gv = ((const float4*)g)[tid];
  float4 bv = ((const float4*)b)[tid];
  float4 o;
  o.x = (v.x - mu) * rstd * gv.x + bv.x;
  o.y = (v.y - mu) * rstd * gv.y + bv.y;
  o.z = (v.z - mu) * rstd * gv.z + bv.z;
  o.w = (v.w - mu) * rstd * gv.w + bv.w;
  ((float4*)outr)[tid] = o;
}

// ---------------- Generic 64x64x16 tiled fp32 GEMM with fused epilogues ----------------
// MODE_QKV : B is per-head stacked weight [H, K, 64]; out written to [B,H,S,64]
// MODE_PROJ: out = resid + A@W + bias           (write to d_out)
// MODE_FF1 : out = gelu_exact(A@W + bias)
// MODE_FF2 : out = out + A@W + bias             (in-place residual from d_out)
#define MODE_QKV 0
#define MODE_PROJ 1
#define MODE_FF1 2
#define MODE_FF2 3

template <int MODE>
__global__ __launch_bounds__(256) void gemm64(const float* __restrict__ A,
                                              const float* __restrict__ W,
                                              const float* __restrict__ bias,
                                              const float* __restrict__ resid,
                                              float* __restrict__ out,
                                              int M, int N, int K) {
  __shared__ float As[16][65];  // padded: avoid 16-way write conflict
  __shared__ float Bs[16][64];
  const int m0 = blockIdx.y * 64;
  const int n0 = blockIdx.x * 64;
  const int tid = threadIdx.x;
  const int tx = tid & 15, ty = tid >> 4;

  // For QKV: tile columns all live in head n0>>6 (BN=64 aligned to head size)
  const float* Wp = (MODE == MODE_QKV) ? (W + (size_t)(n0 >> 6) * K * 64) : (W + n0);

  float acc[4][4] = {};

  for (int k0 = 0; k0 < K; k0 += 16) {
    #pragma unroll
    for (int i = 0; i < 4; ++i) {
      int e = tid + i * 256;
      int r = e >> 4, c = e & 15;
      As[c][r] = A[(size_t)(m0 + r) * K + (k0 + c)];
    }
    #pragma unroll
    for (int i = 0; i < 4; ++i) {
      int e = tid + i * 256;
      int r = e >> 6, c = e & 63;
      if (MODE == MODE_QKV)
        Bs[r][c] = Wp[(size_t)(k0 + r) * 64 + c];
      else
        Bs[r][c] = Wp[(size_t)(k0 + r) * N + c];
    }
    __syncthreads();
    #pragma unroll
    for (int kk = 0; kk < 16; ++kk) {
      float a[4], b[4];
      #pragma unroll
      for (int i = 0; i < 4; ++i) a[i] = As[kk][ty + 16 * i];
      #pragma unroll
      for (int j = 0; j < 4; ++j) b[j] = Bs[kk][tx + 16 * j];
      #pragma unroll
      for (int i = 0; i < 4; ++i)
        #pragma unroll
        for (int j = 0; j < 4; ++j)
          acc[i][j] += a[i] * b[j];
    }
    __syncthreads();
  }

  #pragma unroll
  for (int i = 0; i < 4; ++i) {
    int m = m0 + ty + 16 * i;
    #pragma unroll
    for (int j = 0; j < 4; ++j) {
      int n = n0 + tx + 16 * j;
      float val = acc[i][j];
      if (MODE == MODE_QKV) {
        int b = m >> 10, s = m & (S_ - 1);
        int h = n >> 6, e2 = n & 63;
        out[((size_t)(b * H_ + h) * S_ + s) * HD_ + e2] = val;
      } else if (MODE == MODE_PROJ) {
        out[(size_t)m * N + n] = resid[(size_t)m * N + n] + val + bias[n];
      } else if (MODE == MODE_FF1) {
        val += bias[n];
        out[(size_t)m * N + n] =
            0.5f * val * (1.0f + erff(val * 0.70710678118654752f));
      } else {  // MODE_FF2, in-place residual
        out[(size_t)m * N + n] = out[(size_t)m * N + n] + val + bias[n];
      }
    }
  }
}

// ---------------- Attention: one block handles 8 q-rows of one (b,h) ----------------
__global__ __launch_bounds__(256) void attn_kernel(const float* __restrict__ q,
                                                   const float* __restrict__ k,
                                                   const float* __restrict__ v,
                                                   float* __restrict__ outC) {
  __shared__ float qs[8][64];
  __shared__ float sc[8][1024];
  __shared__ float part[4][8][64];
  __shared__ float rinv[8];

  int bh = blockIdx.x >> 7;            // S/8 = 128 row-blocks per (b,h)
  int r0 = (blockIdx.x & 127) * 8;
  const float* Q = q + (size_t)bh * S_ * HD_;
  const float* K_ = k + (size_t)bh * S_ * HD_;
  const float* V_ = v + (size_t)bh * S_ * HD_;
  int tid = threadIdx.x;

  for (int e = tid; e < 8 * 64; e += 256)
    qs[e >> 6][e & 63] = Q[(size_t)(r0 + (e >> 6)) * HD_ + (e & 63)] * 0.125f;
  __syncthreads();

  // phase 1: scores for 8 rows; each thread owns t = tid, tid+256, ...
  for (int t = tid; t < S_; t += 256) {
    float accs[8] = {};
    const float4* kr = (const float4*)(K_ + (size_t)t * HD_);
    #pragma unroll
    for (int c = 0; c < 16; ++c) {
      float4 k4 = kr[c];
      #pragma unroll
      for (int r = 0; r < 8; ++r) {
        accs[r] += qs[r][c * 4 + 0] * k4.x + qs[r][c * 4 + 1] * k4.y +
                   qs[r][c * 4 + 2] * k4.z + qs[r][c * 4 + 3] * k4.w;
      }
    }
    #pragma unroll
    for (int r = 0; r < 8; ++r) sc[r][t] = accs[r];
  }
  __syncthreads();

  // softmax: 32-thread group per row
  {
    int g = tid >> 5, lane = tid & 31;
    float mx = -1e30f;
    for (int t = lane; t < S_; t += 32) mx = fmaxf(mx, sc[g][t]);
    #pragma unroll
    for (int m = 1; m < 32; m <<= 1) mx = fmaxf(mx, __shfl_xor(mx, m));
    float sum = 0.f;
    for (int t = lane; t < S_; t += 32) {
      float p = expf(sc[g][t] - mx);
      sc[g][t] = p;
      sum += p;
    }
    #pragma unroll
    for (int m = 1; m < 32; m <<= 1) sum += __shfl_xor(sum, m);
    if (lane == 0) rinv[g] = 1.0f / sum;
  }
  __syncthreads();

  // phase 2: O[r][e] = sum_t p[r][t] * V[t][e]; 4 t-groups, reduce in LDS
  int e = tid & 63, tg = tid >> 6;
  float oacc[8] = {};
  for (int t = tg; t < S_; t += 4) {
    float vv = V_[(size_t)t * HD_ + e];
    #pragma unroll
    for (int r = 0; r < 8; ++r) oacc[r] += sc[r][t] * vv;
  }
  #pragma unroll
  for (int r = 0; r < 8; ++r) part[tg][r][e] = oacc[r];
  __syncthreads();

  int b = bh >> 4, h = bh & 15;  // H_ = 16
  for (int idx = tid; idx < 8 * 64; idx += 256) {
    int r = idx >> 6, e2 = idx & 63;
    float o = (part[0][r][e2] + part[1][r][e2] + part[2][r][e2] +
               part[3][r][e2]) * rinv[r];
    outC[((size_t)(b * S_ + (r0 + r))) * D_ + h * HD_ + e2] = o;
  }
}

extern "C" void kernel_launch(void* const* d_in, const int* in_sizes, int n_in,
                              void* d_out, int out_size, void* d_ws, size_t ws_size,
                              hipStream_t stream) {
  const float* x   = (const float*)d_in[0];
  const float* Wq  = (const float*)d_in[1];
  const float* Wk  = (const float*)d_in[2];
  const float* Wv  = (const float*)d_in[3];
  const float* Wo  = (const float*)d_in[4];
  const float* bo  = (const float*)d_in[5];
  const float* W1  = (const float*)d_in[6];
  const float* b1  = (const float*)d_in[7];
  const float* W2  = (const float*)d_in[8];
  const float* b2  = (const float*)d_in[9];
  const float* g1  = (const float*)d_in[10];
  const float* bl1 = (const float*)d_in[11];
  const float* g2  = (const float*)d_in[12];
  const float* bl2 = (const float*)d_in[13];
  float* out = (float*)d_out;

  const size_t MN = (size_t)B_ * S_ * D_;  // 8.39M elements
  float* h  = (float*)d_ws;   // LN1 out; reused as attn-concat, then LN2 out
  float* qb = h + MN;
  float* kb = qb + MN;
  float* vb = kb + MN;
  float* attnC = h;           // alias: h is dead after QKV projections
  float* ff1 = qb;            // alias: qb dead after attention

  const int rows = B_ * S_;   // 8192
  dim3 gg(D_ / 64, rows / 64);

  ln_kernel<<<rows, 256, 0, stream>>>(x, g1, bl1, h);
  gemm64<MODE_QKV><<<gg, 256, 0, stream>>>(h, Wq, nullptr, nullptr, qb, rows, D_, D_);
  gemm64<MODE_QKV><<<gg, 256, 0, stream>>>(h, Wk, nullptr, nullptr, kb, rows, D_, D_);
  gemm64<MODE_QKV><<<gg, 256, 0, stream>>>(h, Wv, nullptr, nullptr, vb, rows, D_, D_);
  attn_kernel<<<B_ * H_ * (S_ / 8), 256, 0, stream>>>(qb, kb, vb, attnC);
  gemm64<MODE_PROJ><<<gg, 256, 0, stream>>>(attnC, Wo, bo, x, out, rows, D_, D_);
  ln_kernel<<<rows, 256, 0, stream>>>(out, g2, bl2, h);
  gemm64<MODE_FF1><<<gg, 256, 0, stream>>>(h, W1, b1, nullptr, ff1, rows, D_, D_);
  gemm64<MODE_FF2><<<gg, 256, 0, stream>>>(ff1, W2, b2, nullptr, out, rows, D_, D_);
}

// Round 2
// 2051.613 us; speedup vs baseline: 3.6207x; 3.6207x over previous
//
#include <hip/hip_runtime.h>
#include <hip/hip_bf16.h>
#include <math.h>

#define B_ 8
#define S_ 1024
#define D_ 1024
#define H_ 16
#define HD_ 64

typedef __bf16 bf16x8 __attribute__((ext_vector_type(8)));
typedef float f32x4 __attribute__((ext_vector_type(4)));

// ---------------- LayerNorm: one block (256 thr) per row of 1024 ----------------
__global__ __launch_bounds__(256) void ln_kernel(const float* __restrict__ x,
                                                 const float* __restrict__ g,
                                                 const float* __restrict__ b,
                                                 float* __restrict__ out) {
  int row = blockIdx.x;
  const float* xr = x + (size_t)row * D_;
  float* outr = out + (size_t)row * D_;
  int tid = threadIdx.x;

  float4 v = ((const float4*)xr)[tid];
  float s = v.x + v.y + v.z + v.w;
  float ss = v.x * v.x + v.y * v.y + v.z * v.z + v.w * v.w;

  #pragma unroll
  for (int m = 1; m < 64; m <<= 1) {
    s += __shfl_xor(s, m);
    ss += __shfl_xor(ss, m);
  }
  __shared__ float red[10];
  int wid = tid >> 6;
  if ((tid & 63) == 0) { red[wid] = s; red[4 + wid] = ss; }
  __syncthreads();
  if (tid == 0) {
    float ts = red[0] + red[1] + red[2] + red[3];
    float tss = red[4] + red[5] + red[6] + red[7];
    float mu = ts * (1.0f / D_);
    float var = tss * (1.0f / D_) - mu * mu;
    red[8] = mu;
    red[9] = rsqrtf(var + 1e-5f);
  }
  __syncthreads();
  float mu = red[8], rstd = red[9];
  float4 gv = ((const float4*)g)[tid];
  float4 bv = ((const float4*)b)[tid];
  float4 o;
  o.x = (v.x - mu) * rstd * gv.x + bv.x;
  o.y = (v.y - mu) * rstd * gv.y + bv.y;
  o.z = (v.z - mu) * rstd * gv.z + bv.z;
  o.w = (v.w - mu) * rstd * gv.w + bv.w;
  ((float4*)outr)[tid] = o;
}

// ---------------- Generic 64x64x16 tiled fp32 GEMM with fused epilogues ----------------
#define MODE_QKV 0
#define MODE_PROJ 1
#define MODE_FF1 2
#define MODE_FF2 3

template <int MODE>
__global__ __launch_bounds__(256) void gemm64(const float* __restrict__ A,
                                              const float* __restrict__ W,
                                              const float* __restrict__ bias,
                                              const float* __restrict__ resid,
                                              float* __restrict__ out,
                                              __hip_bfloat16* __restrict__ outb,
                                              int M, int N, int K) {
  __shared__ float As[16][65];
  __shared__ float Bs[16][64];
  const int m0 = blockIdx.y * 64;
  const int n0 = blockIdx.x * 64;
  const int tid = threadIdx.x;
  const int tx = tid & 15, ty = tid >> 4;

  const float* Wp = (MODE == MODE_QKV) ? (W + (size_t)(n0 >> 6) * K * 64) : (W + n0);

  float acc[4][4] = {};

  for (int k0 = 0; k0 < K; k0 += 16) {
    #pragma unroll
    for (int i = 0; i < 4; ++i) {
      int e = tid + i * 256;
      int r = e >> 4, c = e & 15;
      As[c][r] = A[(size_t)(m0 + r) * K + (k0 + c)];
    }
    #pragma unroll
    for (int i = 0; i < 4; ++i) {
      int e = tid + i * 256;
      int r = e >> 6, c = e & 63;
      if (MODE == MODE_QKV)
        Bs[r][c] = Wp[(size_t)(k0 + r) * 64 + c];
      else
        Bs[r][c] = Wp[(size_t)(k0 + r) * N + c];
    }
    __syncthreads();
    #pragma unroll
    for (int kk = 0; kk < 16; ++kk) {
      float a[4], b[4];
      #pragma unroll
      for (int i = 0; i < 4; ++i) a[i] = As[kk][ty + 16 * i];
      #pragma unroll
      for (int j = 0; j < 4; ++j) b[j] = Bs[kk][tx + 16 * j];
      #pragma unroll
      for (int i = 0; i < 4; ++i)
        #pragma unroll
        for (int j = 0; j < 4; ++j)
          acc[i][j] += a[i] * b[j];
    }
    __syncthreads();
  }

  #pragma unroll
  for (int i = 0; i < 4; ++i) {
    int m = m0 + ty + 16 * i;
    #pragma unroll
    for (int j = 0; j < 4; ++j) {
      int n = n0 + tx + 16 * j;
      float val = acc[i][j];
      if (MODE == MODE_QKV) {
        int b = m >> 10, s = m & (S_ - 1);
        int h = n >> 6, e2 = n & 63;
        outb[((size_t)(b * H_ + h) * S_ + s) * HD_ + e2] = __float2bfloat16(val);
      } else if (MODE == MODE_PROJ) {
        out[(size_t)m * N + n] = resid[(size_t)m * N + n] + val + bias[n];
      } else if (MODE == MODE_FF1) {
        val += bias[n];
        out[(size_t)m * N + n] =
            0.5f * val * (1.0f + erff(val * 0.70710678118654752f));
      } else {
        out[(size_t)m * N + n] = out[(size_t)m * N + n] + val + bias[n];
      }
    }
  }
}

// ---------------- Flash attention, bf16 MFMA 16x16x32 ----------------
// Block = 256 thr (4 waves). Each block: 64 q-rows of one (b,h); wave w owns 16.
// K/V iterated in 64-row tiles. V staged transposed in LDS; K read from global.
// Fragment conventions (gfx950):
//   A-frag: elem j of lane l = A[m = l&15][k = 8*(l>>4) + j]
//   B-frag: elem j of lane l = B[k = 8*(l>>4) + j][n = l&15]   (i.e. B^T row-major)
//   C/D:    col = l&15, row = 4*(l>>4) + reg                    (verified m89/m91)
__global__ __launch_bounds__(256) void fattn(const __hip_bfloat16* __restrict__ q,
                                             const __hip_bfloat16* __restrict__ k,
                                             const __hip_bfloat16* __restrict__ v,
                                             float* __restrict__ outC) {
  __shared__ __align__(16) __bf16 Vt[64][72];      // V^T tile, padded: 144B row stride
  __shared__ __align__(16) __bf16 P[4][16][72];    // per-wave P tile (A-layout source)

  const int bh = blockIdx.x >> 4;
  const int qt = blockIdx.x & 15;
  const int tid = threadIdx.x;
  const int w = tid >> 6, l = tid & 63;
  const int lr = l & 15, lg = l >> 4;

  const size_t base = (size_t)bh * S_ * HD_;
  const int qrow0 = qt * 64 + w * 16;

  // Q a-frags (persist in registers)
  bf16x8 qf0, qf1;
  {
    const __bf16* qp = (const __bf16*)q + base + (size_t)(qrow0 + lr) * HD_ + lg * 8;
    qf0 = *(const bf16x8*)(qp);
    qf1 = *(const bf16x8*)(qp + 32);
  }

  f32x4 oacc[4] = {{0,0,0,0},{0,0,0,0},{0,0,0,0},{0,0,0,0}};
  float m_run[4] = {-1e30f, -1e30f, -1e30f, -1e30f};
  float l_run[4] = {0.f, 0.f, 0.f, 0.f};

  const int vt_t = tid >> 2;
  const int vt_e0 = (tid & 3) * 16;

  for (int t0 = 0; t0 < S_; t0 += 64) {
    __syncthreads();  // protect previous tile's Vt reads
    {
      const __bf16* vp = (const __bf16*)v + base + (size_t)(t0 + vt_t) * HD_ + vt_e0;
      bf16x8 v0 = *(const bf16x8*)vp;
      bf16x8 v1 = *(const bf16x8*)(vp + 8);
      #pragma unroll
      for (int i = 0; i < 8; ++i) Vt[vt_e0 + i][vt_t] = v0[i];
      #pragma unroll
      for (int i = 0; i < 8; ++i) Vt[vt_e0 + 8 + i][vt_t] = v1[i];
    }
    __syncthreads();

    // ---- scores: 4 tiles of 16 q-rows x 16 k-rows, K = 64 (2 chunks) ----
    f32x4 sacc[4];
    const __bf16* kp = (const __bf16*)k + base + (size_t)(t0 + lr) * HD_ + lg * 8;
    #pragma unroll
    for (int g = 0; g < 4; ++g) {
      bf16x8 kf0 = *(const bf16x8*)(kp + (size_t)g * 16 * HD_);
      bf16x8 kf1 = *(const bf16x8*)(kp + (size_t)g * 16 * HD_ + 32);
      f32x4 z = {0.f, 0.f, 0.f, 0.f};
      z = __builtin_amdgcn_mfma_f32_16x16x32_bf16(qf0, kf0, z, 0, 0, 0);
      sacc[g] = __builtin_amdgcn_mfma_f32_16x16x32_bf16(qf1, kf1, z, 0, 0, 0);
    }

    // ---- online softmax, per reg-row r (q-row = 4*lg + r) ----
    #pragma unroll
    for (int r = 0; r < 4; ++r) {
      float tm = fmaxf(fmaxf(sacc[0][r], sacc[1][r]),
                       fmaxf(sacc[2][r], sacc[3][r])) * 0.125f;
      #pragma unroll
      for (int mk = 1; mk < 16; mk <<= 1) tm = fmaxf(tm, __shfl_xor(tm, mk));
      float mn = fmaxf(m_run[r], tm);
      float corr = __expf(m_run[r] - mn);
      float ps = 0.f;
      #pragma unroll
      for (int g = 0; g < 4; ++g) {
        float p = __expf(sacc[g][r] * 0.125f - mn);
        ps += p;
        P[w][4 * lg + r][16 * g + lr] = (__bf16)p;
      }
      #pragma unroll
      for (int mk = 1; mk < 16; mk <<= 1) ps += __shfl_xor(ps, mk);
      l_run[r] = l_run[r] * corr + ps;
      m_run[r] = mn;
      #pragma unroll
      for (int g = 0; g < 4; ++g) oacc[g][r] *= corr;
    }

    // ---- PV: O[16 x 64] += P[16 x 64] @ V[64 x 64] ----
    bf16x8 pa0 = *(const bf16x8*)&P[w][lr][lg * 8];
    bf16x8 pa1 = *(const bf16x8*)&P[w][lr][32 + lg * 8];
    #pragma unroll
    for (int g = 0; g < 4; ++g) {
      bf16x8 vf0 = *(const bf16x8*)&Vt[16 * g + lr][lg * 8];
      bf16x8 vf1 = *(const bf16x8*)&Vt[16 * g + lr][32 + lg * 8];
      oacc[g] = __builtin_amdgcn_mfma_f32_16x16x32_bf16(pa0, vf0, oacc[g], 0, 0, 0);
      oacc[g] = __builtin_amdgcn_mfma_f32_16x16x32_bf16(pa1, vf1, oacc[g], 0, 0, 0);
    }
  }

  // ---- epilogue: O /= l, scatter to [B,S,D] concat layout ----
  const int b = bh >> 4, hh = bh & 15;
  #pragma unroll
  for (int r = 0; r < 4; ++r) {
    float inv = 1.0f / l_run[r];
    int srow = qrow0 + 4 * lg + r;
    float* op = outC + ((size_t)(b * S_ + srow)) * D_ + hh * HD_;
    #pragma unroll
    for (int g = 0; g < 4; ++g) op[16 * g + lr] = oacc[g][r] * inv;
  }
}

extern "C" void kernel_launch(void* const* d_in, const int* in_sizes, int n_in,
                              void* d_out, int out_size, void* d_ws, size_t ws_size,
                              hipStream_t stream) {
  const float* x   = (const float*)d_in[0];
  const float* Wq  = (const float*)d_in[1];
  const float* Wk  = (const float*)d_in[2];
  const float* Wv  = (const float*)d_in[3];
  const float* Wo  = (const float*)d_in[4];
  const float* bo  = (const float*)d_in[5];
  const float* W1  = (const float*)d_in[6];
  const float* b1  = (const float*)d_in[7];
  const float* W2  = (const float*)d_in[8];
  const float* b2  = (const float*)d_in[9];
  const float* g1  = (const float*)d_in[10];
  const float* bl1 = (const float*)d_in[11];
  const float* g2  = (const float*)d_in[12];
  const float* bl2 = (const float*)d_in[13];
  float* out = (float*)d_out;

  const size_t MN = (size_t)B_ * S_ * D_;
  float* h = (float*)d_ws;                                   // LN out (fp32)
  __hip_bfloat16* qb = (__hip_bfloat16*)(h + MN);            // [B,H,S,64] bf16
  __hip_bfloat16* kb = qb + MN;
  __hip_bfloat16* vb = kb + MN;
  float* attnC = h;            // alias: h dead after QKV projections
  float* ff1 = (float*)qb;     // alias: q/k/v dead after attention (spans qb+kb)

  const int rows = B_ * S_;
  dim3 gg(D_ / 64, rows / 64);

  ln_kernel<<<rows, 256, 0, stream>>>(x, g1, bl1, h);
  gemm64<MODE_QKV><<<gg, 256, 0, stream>>>(h, Wq, nullptr, nullptr, nullptr, qb, rows, D_, D_);
  gemm64<MODE_QKV><<<gg, 256, 0, stream>>>(h, Wk, nullptr, nullptr, nullptr, kb, rows, D_, D_);
  gemm64<MODE_QKV><<<gg, 256, 0, stream>>>(h, Wv, nullptr, nullptr, nullptr, vb, rows, D_, D_);
  fattn<<<B_ * H_ * (S_ / 64), 256, 0, stream>>>(qb, kb, vb, attnC);
  gemm64<MODE_PROJ><<<gg, 256, 0, stream>>>(attnC, Wo, bo, x, out, nullptr, rows, D_, D_);
  ln_kernel<<<rows, 256, 0, stream>>>(out, g2, bl2, h);
  gemm64<MODE_FF1><<<gg, 256, 0, stream>>>(h, W1, b1, nullptr, ff1, nullptr, rows, D_, D_);
  gemm64<MODE_FF2><<<gg, 256, 0, stream>>>(ff1, W2, b2, nullptr, out, nullptr, rows, D_, D_);
}

// Round 3
// 363.206 us; speedup vs baseline: 20.4521x; 5.6486x over previous
//
#include <hip/hip_runtime.h>
#include <hip/hip_bf16.h>
#include <math.h>

#define B_ 8
#define S_ 1024
#define D_ 1024
#define H_ 16
#define HD_ 64

typedef __bf16 bf16x8 __attribute__((ext_vector_type(8)));
typedef __bf16 bf16x4 __attribute__((ext_vector_type(4)));
typedef float f32x4 __attribute__((ext_vector_type(4)));

__device__ __forceinline__ void gld_lds16(const __bf16* g, __bf16* l) {
  __builtin_amdgcn_global_load_lds(
      (const __attribute__((address_space(1))) void*)g,
      (__attribute__((address_space(3))) void*)l, 16, 0, 0);
}

// ---------------- LayerNorm: fp32 in, bf16 out ----------------
__global__ __launch_bounds__(256) void ln_kernel(const float* __restrict__ x,
                                                 const float* __restrict__ g,
                                                 const float* __restrict__ b,
                                                 __bf16* __restrict__ out) {
  int row = blockIdx.x;
  const float* xr = x + (size_t)row * D_;
  __bf16* outr = out + (size_t)row * D_;
  int tid = threadIdx.x;

  float4 v = ((const float4*)xr)[tid];
  float s = v.x + v.y + v.z + v.w;
  float ss = v.x * v.x + v.y * v.y + v.z * v.z + v.w * v.w;

  #pragma unroll
  for (int m = 1; m < 64; m <<= 1) {
    s += __shfl_xor(s, m);
    ss += __shfl_xor(ss, m);
  }
  __shared__ float red[10];
  int wid = tid >> 6;
  if ((tid & 63) == 0) { red[wid] = s; red[4 + wid] = ss; }
  __syncthreads();
  if (tid == 0) {
    float ts = red[0] + red[1] + red[2] + red[3];
    float tss = red[4] + red[5] + red[6] + red[7];
    float mu = ts * (1.0f / D_);
    float var = tss * (1.0f / D_) - mu * mu;
    red[8] = mu;
    red[9] = rsqrtf(var + 1e-5f);
  }
  __syncthreads();
  float mu = red[8], rstd = red[9];
  float4 gv = ((const float4*)g)[tid];
  float4 bv = ((const float4*)b)[tid];
  bf16x4 o;
  o[0] = (__bf16)((v.x - mu) * rstd * gv.x + bv.x);
  o[1] = (__bf16)((v.y - mu) * rstd * gv.y + bv.y);
  o[2] = (__bf16)((v.z - mu) * rstd * gv.z + bv.z);
  o[3] = (__bf16)((v.w - mu) * rstd * gv.w + bv.w);
  *(bf16x4*)(outr + tid * 4) = o;
}

// ---------------- Weight transpose+convert: fp32 [1024][1024] -> bf16 [N][K] ----------------
__global__ __launch_bounds__(256) void transpose_w(const float* __restrict__ in,
                                                   __bf16* __restrict__ out) {
  __shared__ float t[64][65];
  const int n0 = blockIdx.x * 64, k0 = blockIdx.y * 64;
  const int tid = threadIdx.x;
  const int r = tid >> 4, c4 = (tid & 15) * 4;
  #pragma unroll
  for (int i = 0; i < 4; ++i) {
    float4 v = *(const float4*)&in[(size_t)(k0 + i * 16 + r) * D_ + n0 + c4];
    t[i * 16 + r][c4 + 0] = v.x;
    t[i * 16 + r][c4 + 1] = v.y;
    t[i * 16 + r][c4 + 2] = v.z;
    t[i * 16 + r][c4 + 3] = v.w;
  }
  __syncthreads();
  #pragma unroll
  for (int i = 0; i < 4; ++i) {
    bf16x4 o;
    #pragma unroll
    for (int j = 0; j < 4; ++j) o[j] = (__bf16)t[c4 + j][i * 16 + r];
    *(bf16x4*)&out[(size_t)(n0 + i * 16 + r) * D_ + k0 + c4] = o;
  }
}

// ---- QKV weights: [H][D][HD] fp32 (x3) -> bf16 rows n = which*1024 + h*64 + e, col k = d ----
__global__ __launch_bounds__(256) void transpose_qkv(const float* __restrict__ Wq,
                                                     const float* __restrict__ Wk,
                                                     const float* __restrict__ Wv,
                                                     __bf16* __restrict__ out) {
  __shared__ float t[64][65];
  const int d0 = blockIdx.x * 64;
  const int h = blockIdx.y;
  const int which = blockIdx.z;
  const float* in = (which == 0 ? Wq : which == 1 ? Wk : Wv) + (size_t)h * D_ * HD_;
  const int tid = threadIdx.x;
  const int r = tid >> 4, c4 = (tid & 15) * 4;
  #pragma unroll
  for (int i = 0; i < 4; ++i) {
    float4 v = *(const float4*)&in[(size_t)(d0 + i * 16 + r) * HD_ + c4];
    t[i * 16 + r][c4 + 0] = v.x;
    t[i * 16 + r][c4 + 1] = v.y;
    t[i * 16 + r][c4 + 2] = v.z;
    t[i * 16 + r][c4 + 3] = v.w;
  }
  __syncthreads();
  #pragma unroll
  for (int i = 0; i < 4; ++i) {
    bf16x4 o;
    #pragma unroll
    for (int j = 0; j < 4; ++j) o[j] = (__bf16)t[c4 + j][i * 16 + r];
    *(bf16x4*)&out[(size_t)(which * 1024 + h * 64 + i * 16 + r) * D_ + d0 + c4] = o;
  }
}

// ---------------- bf16 MFMA GEMM, m97 structure: 128x128 tile, BK=64 ----------------
// A [M][K] bf16 row-major; Bt [N][K] bf16 (transposed weight).
// Fragments (gfx950, 16x16x32): A elem j lane l = A[m=l&15][k=8*(l>>4)+j];
// B elem j lane l = B[k=8*(l>>4)+j][n=l&15] (= Bt row n); C/D: col=l&15, row=4*(l>>4)+reg.
#define MODE_QKV 0
#define MODE_PROJ 1
#define MODE_FF1 2
#define MODE_FF2 3

template <int MODE>
__global__ __launch_bounds__(256) void gemm_mfma(const __bf16* __restrict__ A,
                                                 const __bf16* __restrict__ Bt,
                                                 const float* __restrict__ bias,
                                                 const float* __restrict__ resid,
                                                 float* __restrict__ outf,
                                                 __bf16* __restrict__ outb,
                                                 int M, int N, int K) {
  __shared__ __align__(16) __bf16 As[128 * 64];
  __shared__ __align__(16) __bf16 Bs[128 * 64];
  const int tid = threadIdx.x;
  const int m0 = blockIdx.y * 128, n0 = blockIdx.x * 128;
  const int w = tid >> 6, l = tid & 63, lr = l & 15, lg = l >> 4;
  const int wm = (w >> 1) * 64, wn = (w & 1) * 64;

  f32x4 acc[4][4] = {};

  for (int k0 = 0; k0 < K; k0 += 64) {
    __syncthreads();  // previous tile's reads complete before overwrite
    #pragma unroll
    for (int i = 0; i < 4; ++i) {
      int e = i * 256 + tid;
      gld_lds16(A + (size_t)(m0 + (e >> 3)) * K + k0 + (e & 7) * 8, &As[e * 8]);
    }
    #pragma unroll
    for (int i = 0; i < 4; ++i) {
      int e = i * 256 + tid;
      gld_lds16(Bt + (size_t)(n0 + (e >> 3)) * K + k0 + (e & 7) * 8, &Bs[e * 8]);
    }
    asm volatile("s_waitcnt vmcnt(0)");
    __syncthreads();

    #pragma unroll
    for (int kk = 0; kk < 2; ++kk) {
      bf16x8 af[4], bfr[4];
      #pragma unroll
      for (int i = 0; i < 4; ++i)
        af[i] = *(const bf16x8*)&As[(wm + i * 16 + lr) * 64 + kk * 32 + lg * 8];
      #pragma unroll
      for (int j = 0; j < 4; ++j)
        bfr[j] = *(const bf16x8*)&Bs[(wn + j * 16 + lr) * 64 + kk * 32 + lg * 8];
      #pragma unroll
      for (int i = 0; i < 4; ++i)
        #pragma unroll
        for (int j = 0; j < 4; ++j)
          acc[i][j] = __builtin_amdgcn_mfma_f32_16x16x32_bf16(af[i], bfr[j], acc[i][j], 0, 0, 0);
    }
  }

  #pragma unroll
  for (int i = 0; i < 4; ++i) {
    #pragma unroll
    for (int j = 0; j < 4; ++j) {
      #pragma unroll
      for (int r = 0; r < 4; ++r) {
        int m = m0 + wm + i * 16 + 4 * lg + r;
        int n = n0 + wn + j * 16 + lr;
        float val = acc[i][j][r];
        if (MODE == MODE_QKV) {
          int b = m >> 10, s = m & 1023;
          int which = n >> 10, hh = (n >> 6) & 15, e = n & 63;
          outb[(size_t)which * 8388608 + ((size_t)(b * 16 + hh) * 1024 + s) * 64 + e] =
              (__bf16)val;
        } else if (MODE == MODE_PROJ) {
          size_t idx = (size_t)m * 1024 + n;
          outf[idx] = resid[idx] + val + bias[n];
        } else if (MODE == MODE_FF1) {
          val += bias[n];
          outb[(size_t)m * 1024 + n] =
              (__bf16)(0.5f * val * (1.0f + erff(val * 0.70710678118654752f)));
        } else {  // MODE_FF2: in-place residual on fp32 out
          size_t idx = (size_t)m * 1024 + n;
          outf[idx] = outf[idx] + val + bias[n];
        }
      }
    }
  }
}

// ---------------- Flash attention, bf16 MFMA 16x16x32 (bf16 out) ----------------
__global__ __launch_bounds__(256) void fattn(const __hip_bfloat16* __restrict__ q,
                                             const __hip_bfloat16* __restrict__ k,
                                             const __hip_bfloat16* __restrict__ v,
                                             __bf16* __restrict__ outC) {
  __shared__ __align__(16) __bf16 Vt[64][72];
  __shared__ __align__(16) __bf16 P[4][16][72];

  const int bh = blockIdx.x >> 4;
  const int qt = blockIdx.x & 15;
  const int tid = threadIdx.x;
  const int w = tid >> 6, l = tid & 63;
  const int lr = l & 15, lg = l >> 4;

  const size_t base = (size_t)bh * S_ * HD_;
  const int qrow0 = qt * 64 + w * 16;

  bf16x8 qf0, qf1;
  {
    const __bf16* qp = (const __bf16*)q + base + (size_t)(qrow0 + lr) * HD_ + lg * 8;
    qf0 = *(const bf16x8*)(qp);
    qf1 = *(const bf16x8*)(qp + 32);
  }

  f32x4 oacc[4] = {{0,0,0,0},{0,0,0,0},{0,0,0,0},{0,0,0,0}};
  float m_run[4] = {-1e30f, -1e30f, -1e30f, -1e30f};
  float l_run[4] = {0.f, 0.f, 0.f, 0.f};

  const int vt_t = tid >> 2;
  const int vt_e0 = (tid & 3) * 16;

  for (int t0 = 0; t0 < S_; t0 += 64) {
    __syncthreads();
    {
      const __bf16* vp = (const __bf16*)v + base + (size_t)(t0 + vt_t) * HD_ + vt_e0;
      bf16x8 v0 = *(const bf16x8*)vp;
      bf16x8 v1 = *(const bf16x8*)(vp + 8);
      #pragma unroll
      for (int i = 0; i < 8; ++i) Vt[vt_e0 + i][vt_t] = v0[i];
      #pragma unroll
      for (int i = 0; i < 8; ++i) Vt[vt_e0 + 8 + i][vt_t] = v1[i];
    }
    __syncthreads();

    f32x4 sacc[4];
    const __bf16* kp = (const __bf16*)k + base + (size_t)(t0 + lr) * HD_ + lg * 8;
    #pragma unroll
    for (int g = 0; g < 4; ++g) {
      bf16x8 kf0 = *(const bf16x8*)(kp + (size_t)g * 16 * HD_);
      bf16x8 kf1 = *(const bf16x8*)(kp + (size_t)g * 16 * HD_ + 32);
      f32x4 z = {0.f, 0.f, 0.f, 0.f};
      z = __builtin_amdgcn_mfma_f32_16x16x32_bf16(qf0, kf0, z, 0, 0, 0);
      sacc[g] = __builtin_amdgcn_mfma_f32_16x16x32_bf16(qf1, kf1, z, 0, 0, 0);
    }

    #pragma unroll
    for (int r = 0; r < 4; ++r) {
      float tm = fmaxf(fmaxf(sacc[0][r], sacc[1][r]),
                       fmaxf(sacc[2][r], sacc[3][r])) * 0.125f;
      #pragma unroll
      for (int mk = 1; mk < 16; mk <<= 1) tm = fmaxf(tm, __shfl_xor(tm, mk));
      float mn = fmaxf(m_run[r], tm);
      float corr = __expf(m_run[r] - mn);
      float ps = 0.f;
      #pragma unroll
      for (int g = 0; g < 4; ++g) {
        float p = __expf(sacc[g][r] * 0.125f - mn);
        ps += p;
        P[w][4 * lg + r][16 * g + lr] = (__bf16)p;
      }
      #pragma unroll
      for (int mk = 1; mk < 16; mk <<= 1) ps += __shfl_xor(ps, mk);
      l_run[r] = l_run[r] * corr + ps;
      m_run[r] = mn;
      #pragma unroll
      for (int g = 0; g < 4; ++g) oacc[g][r] *= corr;
    }

    bf16x8 pa0 = *(const bf16x8*)&P[w][lr][lg * 8];
    bf16x8 pa1 = *(const bf16x8*)&P[w][lr][32 + lg * 8];
    #pragma unroll
    for (int g = 0; g < 4; ++g) {
      bf16x8 vf0 = *(const bf16x8*)&Vt[16 * g + lr][lg * 8];
      bf16x8 vf1 = *(const bf16x8*)&Vt[16 * g + lr][32 + lg * 8];
      oacc[g] = __builtin_amdgcn_mfma_f32_16x16x32_bf16(pa0, vf0, oacc[g], 0, 0, 0);
      oacc[g] = __builtin_amdgcn_mfma_f32_16x16x32_bf16(pa1, vf1, oacc[g], 0, 0, 0);
    }
  }

  const int b = bh >> 4, hh = bh & 15;
  #pragma unroll
  for (int r = 0; r < 4; ++r) {
    float inv = 1.0f / l_run[r];
    int srow = qrow0 + 4 * lg + r;
    __bf16* op = outC + ((size_t)(b * S_ + srow)) * D_ + hh * HD_;
    #pragma unroll
    for (int g = 0; g < 4; ++g) op[16 * g + lr] = (__bf16)(oacc[g][r] * inv);
  }
}

extern "C" void kernel_launch(void* const* d_in, const int* in_sizes, int n_in,
                              void* d_out, int out_size, void* d_ws, size_t ws_size,
                              hipStream_t stream) {
  const float* x   = (const float*)d_in[0];
  const float* Wq  = (const float*)d_in[1];
  const float* Wk  = (const float*)d_in[2];
  const float* Wv  = (const float*)d_in[3];
  const float* Wo  = (const float*)d_in[4];
  const float* bo  = (const float*)d_in[5];
  const float* W1  = (const float*)d_in[6];
  const float* b1  = (const float*)d_in[7];
  const float* W2  = (const float*)d_in[8];
  const float* b2  = (const float*)d_in[9];
  const float* g1  = (const float*)d_in[10];
  const float* bl1 = (const float*)d_in[11];
  const float* g2  = (const float*)d_in[12];
  const float* bl2 = (const float*)d_in[13];
  float* out = (float*)d_out;

  const size_t MN = (size_t)B_ * S_ * D_;  // 8388608
  __bf16* h     = (__bf16*)d_ws;           // LN1 out; later LN2 out
  __bf16* wt    = h + MN;                  // 6144 x 1024 bf16 transposed weights
  __bf16* qkv   = wt + (size_t)6144 * 1024;
  __bf16* attnC = qkv + 3 * MN;
  __bf16* ff1   = attnC + MN;

  __bf16* wqkv_t = wt;                       // rows 0..3071
  __bf16* wo_t   = wt + (size_t)3072 * 1024;
  __bf16* w1_t   = wt + (size_t)4096 * 1024;
  __bf16* w2_t   = wt + (size_t)5120 * 1024;

  const int rows = B_ * S_;  // 8192

  ln_kernel<<<rows, 256, 0, stream>>>(x, g1, bl1, h);
  transpose_qkv<<<dim3(16, 16, 3), 256, 0, stream>>>(Wq, Wk, Wv, wqkv_t);
  transpose_w<<<dim3(16, 16), 256, 0, stream>>>(Wo, wo_t);
  transpose_w<<<dim3(16, 16), 256, 0, stream>>>(W1, w1_t);
  transpose_w<<<dim3(16, 16), 256, 0, stream>>>(W2, w2_t);

  gemm_mfma<MODE_QKV><<<dim3(24, 64), 256, 0, stream>>>(
      h, wqkv_t, nullptr, nullptr, nullptr, qkv, rows, 3072, D_);
  fattn<<<B_ * H_ * (S_ / 64), 256, 0, stream>>>(
      (const __hip_bfloat16*)qkv, (const __hip_bfloat16*)(qkv + MN),
      (const __hip_bfloat16*)(qkv + 2 * MN), attnC);
  gemm_mfma<MODE_PROJ><<<dim3(8, 64), 256, 0, stream>>>(
      attnC, wo_t, bo, x, out, nullptr, rows, D_, D_);
  ln_kernel<<<rows, 256, 0, stream>>>(out, g2, bl2, h);
  gemm_mfma<MODE_FF1><<<dim3(8, 64), 256, 0, stream>>>(
      h, w1_t, b1, nullptr, nullptr, ff1, rows, D_, D_);
  gemm_mfma<MODE_FF2><<<dim3(8, 64), 256, 0, stream>>>(
      ff1, w2_t, b2, nullptr, out, nullptr, rows, D_, D_);
}